// Round 3
// baseline (355.025 us; speedup 1.0000x reference)
//
#include <hip/hip_runtime.h>

// Shapes from reference
#define Bn   4
#define Cn   720
#define Hn   128
#define Wn   128
#define Pn   9
#define OFFn 80           // Cn / Pn
#define HWn  16384        // Hn * Wn  (= 2^14)
#define TPB  1024         // threads per block -> 16 waves/block
#define PRE_TPB 256

// ---------------------------------------------------------------------------
// Kernel 1: precompute per-(b,p,pos) gather record ONCE (instead of 80x, once
// per channel, in the hot kernel). Record = {base=y0*Wn+x0 (int, bit-cast),
// dy, dx, pad} = 16 B. Total Bn*Pn*HWn = 589,824 records = 9 MB in d_ws.
// location = uniform[0,127): corners strictly in-bounds; clamp to [0,126] is
// defensive only (bounds the LDS address in kernel 2).
// ---------------------------------------------------------------------------
__global__ __launch_bounds__(PRE_TPB) void dcn_precompute_kernel(
    const float* __restrict__ loc,
    float4* __restrict__ ws)
{
    const int idx = blockIdx.x * PRE_TPB + threadIdx.x;   // over Bn*Pn*HWn
    const int pos = idx & (HWn - 1);
    const int bp  = idx >> 14;          // b * Pn + p
    const int b   = bp / Pn;
    const int p   = bp - b * Pn;

    const float yq = loc[((size_t)b * (2 * Pn) + 2 * p)     * HWn + pos];
    const float xq = loc[((size_t)b * (2 * Pn) + 2 * p + 1) * HWn + pos];

    const float y0f = floorf(yq);
    const float x0f = floorf(xq);
    const float dy  = yq - y0f;
    const float dx  = xq - x0f;

    int y0 = min(max((int)y0f, 0), Hn - 2);
    int x0 = min(max((int)x0f, 0), Wn - 2);
    const int base = y0 * Wn + x0;

    ws[idx] = make_float4(__int_as_float(base), dy, dx, 0.f);
}

// ---------------------------------------------------------------------------
// Kernel 2: one block per (b, c). Stage plane x[b,c,:,:] (64 KB) into LDS
// coalesced; per position read the precomputed record (one dwordx4, L2/L3-
// resident: each 256 KB (b,p)-slice is reused by 80 channel-blocks), do
// 2x ds_read2_b32 for the 4 corners (offsets {0,1} and {128,129} fit the
// 8-bit ds offset fields), ~10 VALU, store float4.
// 64 KB LDS + TPB=1024 + low VGPR -> 2 blocks/CU = 32 waves/CU.
// ---------------------------------------------------------------------------
__global__ __launch_bounds__(TPB, 8) void dcn_bilinear_ws_kernel(
    const float* __restrict__ x,
    const float4* __restrict__ ws,
    const float* __restrict__ bias,
    float* __restrict__ out)
{
    __shared__ float splane[HWn];   // 64 KB

    const int bc = blockIdx.x;        // b * Cn + c
    const int b  = bc / Cn;
    const int c  = bc - b * Cn;       // global channel
    const int p  = c / OFFn;          // group index

    const int tid = threadIdx.x;

    // ---- Stage the 64 KB plane into LDS, float4-coalesced ----
    {
        const float4* src = (const float4*)(x + (size_t)bc * HWn);
        float4* dst = (float4*)splane;
        #pragma unroll
        for (int k = 0; k < HWn / 4 / TPB; ++k) {       // 4 iterations
            dst[tid + k * TPB] = src[tid + k * TPB];
        }
    }
    __syncthreads();

    const float bv = bias[c];
    const float4* wsp = ws + (size_t)(b * Pn + p) * HWn;   // this group's records
    float4* ob4 = (float4*)(out + (size_t)bc * HWn);

    // ---- Gather: each thread handles 4 float4 chunks = 16 positions ----
    #pragma unroll 2
    for (int k = 0; k < HWn / 4 / TPB; ++k) {           // 4 iterations
        const int q = tid + k * TPB;                    // float4 output index

        float4 r;
        float* rs = &r.x;

        #pragma unroll
        for (int j = 0; j < 4; ++j) {
            const float4 w = wsp[4 * q + j];
            const int   base = __float_as_int(w.x);
            const float dy   = w.y;
            const float dx   = w.z;

            const float* r0 = splane + base;
            const float v00 = r0[0];
            const float v01 = r0[1];
            const float v10 = r0[Wn];
            const float v11 = r0[Wn + 1];

            const float omdy = 1.f - dy;
            const float omdx = 1.f - dx;
            rs[j] = omdy * (omdx * v00 + dx * v01)
                  + dy   * (omdx * v10 + dx * v11) + bv;
        }

        ob4[q] = r;
    }
}

extern "C" void kernel_launch(void* const* d_in, const int* in_sizes, int n_in,
                              void* d_out, int out_size, void* d_ws, size_t ws_size,
                              hipStream_t stream)
{
    const float* x    = (const float*)d_in[0];
    const float* loc  = (const float*)d_in[1];
    const float* bias = (const float*)d_in[2];
    float* out        = (float*)d_out;
    float4* ws        = (float4*)d_ws;     // needs Bn*Pn*HWn*16 = 9.44 MB

    dim3 pgrid(Bn * Pn * HWn / PRE_TPB);   // 2304 blocks
    dcn_precompute_kernel<<<pgrid, PRE_TPB, 0, stream>>>(loc, ws);

    dim3 grid(Bn * Cn);                    // 2880 blocks, one per (b, channel)
    dcn_bilinear_ws_kernel<<<grid, TPB, 0, stream>>>(x, ws, bias, out);
}